// Round 2
// baseline (390.976 us; speedup 1.0000x reference)
//
#include <hip/hip_runtime.h>
#include <hip/hip_bf16.h>

// Problem dims
#define BB 64
#define TT 128
#define FIN 12
#define HH 128
#define GG 512  // 4*H

#define LOG2E 1.4426950408889634f
#define TWO_LOG2E 2.8853900817779268f

__device__ __forceinline__ float fexp2(float x) { return __builtin_amdgcn_exp2f(x); }
__device__ __forceinline__ float frcp(float x)  { return __builtin_amdgcn_rcpf(x); }

// tanh(x) = 1 - 2/(1+e^{2x}); correct limits at +/-inf via exp2->{inf,0}
__device__ __forceinline__ float tanh_f(float x) {
  return 1.0f - 2.0f * frcp(1.0f + fexp2(TWO_LOG2E * x));
}
__device__ __forceinline__ float sigm_f(float x) {
  return frcp(1.0f + fexp2(-LOG2E * x));
}

#define FMA4S(acc, s, v) do { \
  acc.x = fmaf((s), (v).x, acc.x); \
  acc.y = fmaf((s), (v).y, acc.y); \
  acc.z = fmaf((s), (v).z, acc.z); \
  acc.w = fmaf((s), (v).w, acc.w); } while (0)

// ---------------------------------------------------------------------------
// K1: encoder + decoder LSTM. One block per batch element. 1024 threads:
// thread (g = tid&511, kh = tid>>9) owns HALF of gate row g's Whh weights
// (64 floats = 16 float4 in VGPRs -- fits under the 128-VGPR cap of
// launch_bounds(1024,4), so the R1 spill cannot recur). Partials meet in LDS;
// threads tid<128 fold partials + bias, apply activations, update (c,h).
// 2 barriers per step.
// ---------------------------------------------------------------------------
__global__ __launch_bounds__(1024, 4) void lstm_kernel(
    const float* __restrict__ x,
    const float* __restrict__ eWih, const float* __restrict__ eWhh, const float* __restrict__ eb,
    const float* __restrict__ dWih, const float* __restrict__ dWhh, const float* __restrict__ db,
    float* __restrict__ encH, float* __restrict__ decH)
{
  const int b   = blockIdx.x;
  const int tid = threadIdx.x;
  const int g   = tid & 511;   // gate row
  const int kh  = tid >> 9;    // 0/1: k-half of the dot product

  __shared__ __align__(16) float xs[TT * FIN];   // 6 KB
  __shared__ __align__(16) float h_lds[HH];      // 512 B
  __shared__ __align__(16) float part[2 * GG];   // 4 KB, part[2*g+kh]

  // stage this batch's input sequence
  if (tid < (TT * FIN / 4))
    ((float4*)xs)[tid] = ((const float4*)(x + (size_t)b * TT * FIN))[tid];
  if (tid < HH) h_lds[tid] = 0.0f;
  float c = 0.0f;  // live in tid < 128

  #pragma unroll 1
  for (int phase = 0; phase < 2; ++phase) {
    const float* Wih  = phase ? dWih : eWih;
    const float* Whh  = phase ? dWhh : eWhh;
    const float* bias = phase ? db : eb;
    float* Hout       = phase ? decH : encH;

    // per-thread weights: half a gate row
    float4 whh[16];
    #pragma unroll
    for (int j = 0; j < 16; ++j)
      whh[j] = *(const float4*)(Whh + g * HH + kh * 64 + 4 * j);
    float wih[6];
    #pragma unroll
    for (int j = 0; j < 6; ++j)
      wih[j] = Wih[g * FIN + kh * 6 + j];

    // bias for the h-update threads
    float b_i = 0.f, b_f = 0.f, b_g = 0.f, b_o = 0.f;
    if (tid < HH) {
      b_i = bias[tid];
      b_f = bias[HH + tid];
      b_g = bias[2 * HH + tid];
      b_o = bias[3 * HH + tid];
    }

    #pragma unroll 1
    for (int t = 0; t < TT; ++t) {
      __syncthreads();  // h_lds/xs ready; prev-step part reads done
      float a0, a1, a2 = 0.0f, a3 = 0.0f;
      {
        // x contribution: this thread's 6-element slice (wave-uniform LDS reads)
        const float2* xt2 = (const float2*)(xs + t * FIN + kh * 6);
        float2 x0 = xt2[0], x1 = xt2[1], x2 = xt2[2];
        a0 = x0.x * wih[0]; a1 = x0.y * wih[1];
        a0 = fmaf(x1.x, wih[2], a0); a1 = fmaf(x1.y, wih[3], a1);
        a0 = fmaf(x2.x, wih[4], a0); a1 = fmaf(x2.y, wih[5], a1);
      }
      const float* hbase = h_lds + kh * 64;
      #pragma unroll
      for (int k = 0; k < 64; k += 4) {
        float4 h4 = *(const float4*)(hbase + k);  // broadcast read
        a0 = fmaf(h4.x, whh[k >> 2].x, a0);
        a1 = fmaf(h4.y, whh[k >> 2].y, a1);
        a2 = fmaf(h4.z, whh[k >> 2].z, a2);
        a3 = fmaf(h4.w, whh[k >> 2].w, a3);
      }
      part[2 * g + kh] = (a0 + a1) + (a2 + a3);
      __syncthreads();  // partials ready
      if (tid < HH) {
        float2 pi = *(const float2*)&part[2 * tid];
        float2 pf = *(const float2*)&part[2 * (HH + tid)];
        float2 pg = *(const float2*)&part[2 * (2 * HH + tid)];
        float2 po = *(const float2*)&part[2 * (3 * HH + tid)];
        float zi = sigm_f(pi.x + pi.y + b_i);
        float zf = sigm_f(pf.x + pf.y + b_f);
        float zg = tanh_f(pg.x + pg.y + b_g);
        float zo = sigm_f(po.x + po.y + b_o);
        c = fmaf(zf, c, zi * zg);
        float hn = zo * tanh_f(c);
        h_lds[tid] = hn;
        Hout[((size_t)b * TT + t) * HH + tid] = hn;
      }
    }
  }
}

// ---------------------------------------------------------------------------
// K2: A[b,s,h] = decH[b,s,:]·W1[h,:] + attn_b[h]   (m==0)
//     P[b,t,h] = encH[b,t,:]·W2[h,:]               (m==1)
// grid 1024 = (8 row-tiles x 64 b x 2 m), 256 threads, k-halved LDS W^T.
// ---------------------------------------------------------------------------
__global__ __launch_bounds__(256, 2) void proj_kernel(
    const float* __restrict__ encH, const float* __restrict__ decH,
    const float* __restrict__ attnW, const float* __restrict__ attnb,
    float* __restrict__ Abuf, float* __restrict__ Pbuf)
{
  const int m  = blockIdx.x & 1;
  const int b  = (blockIdx.x >> 1) & 63;
  const int r0 = (blockIdx.x >> 7) * 16;
  const int tid = threadIdx.x;

  __shared__ __align__(16) float WT[64 * 128];  // 32 KB: W^T for a k-half
  __shared__ __align__(16) float Xt[16 * 128];  // 8 KB

  const float* X = (m ? encH : decH) + ((size_t)b * TT + r0) * HH;
  const float* W = attnW + (m ? HH : 0);

  ((float4*)Xt)[tid]       = ((const float4*)X)[tid];
  ((float4*)Xt)[256 + tid] = ((const float4*)X)[256 + tid];

  const int hq = tid & 31, rr = tid >> 5;
  const int h0 = 4 * hq;

  float4 acc0, acc1;
  if (m == 0) { acc0 = *(const float4*)(attnb + h0); acc1 = acc0; }
  else        { acc0 = make_float4(0.f, 0.f, 0.f, 0.f); acc1 = acc0; }

  for (int kb = 0; kb < 2; ++kb) {
    __syncthreads();  // protect WT overwrite
    {
      int h = tid >> 1, koff = (tid & 1) * 32;
      #pragma unroll
      for (int j = 0; j < 8; ++j) {
        float4 v = *(const float4*)(W + h * 256 + kb * 64 + koff + 4 * j);
        int kp = koff + 4 * j;
        WT[(kp + 0) * 128 + h] = v.x;
        WT[(kp + 1) * 128 + h] = v.y;
        WT[(kp + 2) * 128 + h] = v.z;
        WT[(kp + 3) * 128 + h] = v.w;
      }
    }
    __syncthreads();
    const float* xr0 = Xt + (2 * rr) * 128 + kb * 64;
    const float* xr1 = xr0 + 128;
    #pragma unroll
    for (int k4 = 0; k4 < 64; k4 += 4) {
      float4 xa = *(const float4*)(xr0 + k4);
      float4 xb = *(const float4*)(xr1 + k4);
      float4 w0 = *(const float4*)&WT[(k4 + 0) * 128 + h0];
      float4 w1 = *(const float4*)&WT[(k4 + 1) * 128 + h0];
      float4 w2 = *(const float4*)&WT[(k4 + 2) * 128 + h0];
      float4 w3 = *(const float4*)&WT[(k4 + 3) * 128 + h0];
      FMA4S(acc0, xa.x, w0); FMA4S(acc0, xa.y, w1);
      FMA4S(acc0, xa.z, w2); FMA4S(acc0, xa.w, w3);
      FMA4S(acc1, xb.x, w0); FMA4S(acc1, xb.y, w1);
      FMA4S(acc1, xb.z, w2); FMA4S(acc1, xb.w, w3);
    }
  }
  float* O = (m ? Pbuf : Abuf) + ((size_t)b * TT + r0) * HH;
  *(float4*)(O + (2 * rr) * 128 + h0)     = acc0;
  *(float4*)(O + (2 * rr + 1) * 128 + h0) = acc1;
}

// ---------------------------------------------------------------------------
// K3: attention + output. Block = (b, 16 decoder steps). 512 threads.
// t halved so LDS stays < 64 KB; P transposed into LDS with XOR-quad swizzle.
// ---------------------------------------------------------------------------
__global__ __launch_bounds__(512, 2) void attn_kernel(
    const float* __restrict__ encH, const float* __restrict__ decH,
    const float* __restrict__ Abuf, const float* __restrict__ Pbuf,
    const float* __restrict__ vw, const float* __restrict__ outW,
    const float* __restrict__ outb, float* __restrict__ out)
{
  const int b  = blockIdx.x >> 3;
  const int s0 = (blockIdx.x & 7) * 16;
  const int tid = threadIdx.x;

  __shared__ __align__(16) float buf[64 * 128];    // 32 KB: P^T-half (swizzled), later encH-half
  __shared__ __align__(16) float a_lds[16 * 128];  // 8 KB: A tile, later ctx
  __shared__ __align__(16) float sc[16 * 128];     // 8 KB: scores -> weights
  __shared__ __align__(16) float dh[16 * 128];     // 8 KB: decH tile
  __shared__ __align__(16) float vl[HH];

  ((float4*)a_lds)[tid] = ((const float4*)(Abuf + ((size_t)b * TT + s0) * HH))[tid];
  ((float4*)dh)[tid]    = ((const float4*)(decH + ((size_t)b * TT + s0) * HH))[tid];
  if (tid < 32) ((float4*)vl)[tid] = ((const float4*)vw)[tid];

  const int u  = tid & 31;
  const int sl = tid >> 5;   // 0..15 decoder-step within tile
  const int uq = u & 15;     // t-quad within half
  const int uh = u >> 4;     // 0/1 h-half

  // ---- energies/scores ----
  for (int half = 0; half < 2; ++half) {
    const int tbase = half * 64;
    __syncthreads();  // prev buf use done (also covers initial staging)
    #pragma unroll
    for (int i = 0; i < 4; ++i) {
      int flat = i * 2048 + tid * 4;
      int tp = flat >> 7;        // 0..63
      int h0 = flat & 127;
      float4 v = *(const float4*)(Pbuf + ((size_t)b * TT + tbase + tp) * HH + h0);
      int tq = tp >> 2, tr = tp & 3;
      buf[(h0 + 0) * 64 + 4 * ((tq ^ ((h0 + 0) >> 2)) & 15) + tr] = v.x;
      buf[(h0 + 1) * 64 + 4 * ((tq ^ ((h0 + 1) >> 2)) & 15) + tr] = v.y;
      buf[(h0 + 2) * 64 + 4 * ((tq ^ ((h0 + 2) >> 2)) & 15) + tr] = v.z;
      buf[(h0 + 3) * 64 + 4 * ((tq ^ ((h0 + 3) >> 2)) & 15) + tr] = v.w;
    }
    __syncthreads();
    float4 acc = make_float4(0.f, 0.f, 0.f, 0.f);
    const float* arow = a_lds + sl * 128;
    #pragma unroll 8
    for (int hh = 0; hh < 64; ++hh) {
      int h = uh * 64 + hh;
      float ah = arow[h];
      float vh = vl[h];
      float4 p4 = *(const float4*)&buf[h * 64 + 4 * ((uq ^ ((h >> 2) & 15)) & 15)];
      acc.x = fmaf(vh, tanh_f(ah + p4.x), acc.x);
      acc.y = fmaf(vh, tanh_f(ah + p4.y), acc.y);
      acc.z = fmaf(vh, tanh_f(ah + p4.z), acc.z);
      acc.w = fmaf(vh, tanh_f(ah + p4.w), acc.w);
    }
    acc.x += __shfl_xor(acc.x, 16, 64);
    acc.y += __shfl_xor(acc.y, 16, 64);
    acc.z += __shfl_xor(acc.z, 16, 64);
    acc.w += __shfl_xor(acc.w, 16, 64);
    if (uh == 0) *(float4*)&sc[sl * 128 + tbase + 4 * uq] = acc;
  }
  __syncthreads();

  // ---- softmax over t (per s row; 32 lanes x f4 = 128) ----
  {
    float4 sv = *(const float4*)&sc[sl * 128 + 4 * u];
    float mx = fmaxf(fmaxf(sv.x, sv.y), fmaxf(sv.z, sv.w));
    #pragma unroll
    for (int msk = 1; msk <= 16; msk <<= 1) mx = fmaxf(mx, __shfl_xor(mx, msk, 64));
    float4 e;
    e.x = fexp2(LOG2E * (sv.x - mx));
    e.y = fexp2(LOG2E * (sv.y - mx));
    e.z = fexp2(LOG2E * (sv.z - mx));
    e.w = fexp2(LOG2E * (sv.w - mx));
    float sm = (e.x + e.y) + (e.z + e.w);
    #pragma unroll
    for (int msk = 1; msk <= 16; msk <<= 1) sm += __shfl_xor(sm, msk, 64);
    float r = frcp(sm);
    e.x *= r; e.y *= r; e.z *= r; e.w *= r;
    *(float4*)&sc[sl * 128 + 4 * u] = e;
  }

  // ---- ctx = w @ encH ----
  float4 ctx = make_float4(0.f, 0.f, 0.f, 0.f);
  const int h0c = 4 * u;
  for (int half = 0; half < 2; ++half) {
    const int tbase = half * 64;
    __syncthreads();  // buf reuse; also orders softmax writes before reads
    #pragma unroll
    for (int i = 0; i < 4; ++i) {
      int flat = i * 2048 + tid * 4;
      int tp = flat >> 7;
      int hh0 = flat & 127;
      *(float4*)&buf[tp * 128 + hh0] =
          *(const float4*)(encH + ((size_t)b * TT + tbase + tp) * HH + hh0);
    }
    __syncthreads();
    const float* wrow = sc + sl * 128 + tbase;
    #pragma unroll 8
    for (int tp = 0; tp < 64; ++tp) {
      float wt = wrow[tp];
      float4 e4 = *(const float4*)&buf[tp * 128 + h0c];
      FMA4S(ctx, wt, e4);
    }
  }
  __syncthreads();
  *(float4*)&a_lds[sl * 128 + h0c] = ctx;  // overlay A tile with ctx
  __syncthreads();

  // ---- out = [decH, ctx] @ outW^T + outb ----
  if (tid < 192) {
    int s = tid / 12, f = tid % 12;
    float acc = outb[f];
    const float4* w4 = (const float4*)(outW + f * 256);
    const float4* d4 = (const float4*)(dh + s * 128);
    const float4* c4 = (const float4*)(a_lds + s * 128);
    #pragma unroll
    for (int k = 0; k < 32; ++k) {
      float4 wv = w4[k], dv = d4[k];
      acc = fmaf(wv.x, dv.x, acc); acc = fmaf(wv.y, dv.y, acc);
      acc = fmaf(wv.z, dv.z, acc); acc = fmaf(wv.w, dv.w, acc);
    }
    #pragma unroll
    for (int k = 0; k < 32; ++k) {
      float4 wv = w4[32 + k], cv = c4[k];
      acc = fmaf(wv.x, cv.x, acc); acc = fmaf(wv.y, cv.y, acc);
      acc = fmaf(wv.z, cv.z, acc); acc = fmaf(wv.w, cv.w, acc);
    }
    out[((size_t)b * TT + s0 + s) * FIN + f] = acc;
  }
}

// ---------------------------------------------------------------------------
extern "C" void kernel_launch(void* const* d_in, const int* in_sizes, int n_in,
                              void* d_out, int out_size, void* d_ws, size_t ws_size,
                              hipStream_t stream)
{
  const float* x     = (const float*)d_in[0];
  const float* eWih  = (const float*)d_in[1];
  const float* eWhh  = (const float*)d_in[2];
  const float* eb    = (const float*)d_in[3];
  const float* dWih  = (const float*)d_in[4];
  const float* dWhh  = (const float*)d_in[5];
  const float* db    = (const float*)d_in[6];
  const float* attnW = (const float*)d_in[7];
  const float* attnb = (const float*)d_in[8];
  const float* vw    = (const float*)d_in[9];
  const float* outW  = (const float*)d_in[10];
  const float* outb  = (const float*)d_in[11];
  float* out = (float*)d_out;

  float* ws   = (float*)d_ws;
  const size_t SEG = (size_t)BB * TT * HH;  // 1,048,576 floats = 4 MB
  float* encH = ws;
  float* decH = ws + SEG;
  float* Abuf = ws + 2 * SEG;
  float* Pbuf = ws + 3 * SEG;

  lstm_kernel<<<64, 1024, 0, stream>>>(x, eWih, eWhh, eb, dWih, dWhh, db, encH, decH);
  proj_kernel<<<1024, 256, 0, stream>>>(encH, decH, attnW, attnb, Abuf, Pbuf);
  attn_kernel<<<512, 512, 0, stream>>>(encH, decH, Abuf, Pbuf, vw, outW, outb, out);
}

// Round 3
// 368.678 us; speedup vs baseline: 1.0605x; 1.0605x over previous
//
#include <hip/hip_runtime.h>
#include <hip/hip_bf16.h>

// Problem dims
#define BB 64
#define TT 128
#define FIN 12
#define HH 128
#define GG 512  // 4*H

#define LOG2E 1.4426950408889634f
#define TWO_LOG2E 2.8853900817779268f

__device__ __forceinline__ float fexp2(float x) { return __builtin_amdgcn_exp2f(x); }
__device__ __forceinline__ float frcp(float x)  { return __builtin_amdgcn_rcpf(x); }

// tanh(x) = 1 - 2/(1+e^{2x}); correct limits at +/-inf via exp2->{inf,0}
__device__ __forceinline__ float tanh_f(float x) {
  return 1.0f - 2.0f * frcp(1.0f + fexp2(TWO_LOG2E * x));
}
__device__ __forceinline__ float sigm_f(float x) {
  return frcp(1.0f + fexp2(-LOG2E * x));
}

#define FMA4S(acc, s, v) do { \
  acc.x = fmaf((s), (v).x, acc.x); \
  acc.y = fmaf((s), (v).y, acc.y); \
  acc.z = fmaf((s), (v).z, acc.z); \
  acc.w = fmaf((s), (v).w, acc.w); } while (0)

#define ACC4(hv, wv, a) do { \
  a = fmaf((hv).x, (wv).x, a); a = fmaf((hv).y, (wv).y, a); \
  a = fmaf((hv).z, (wv).z, a); a = fmaf((hv).w, (wv).w, a); } while (0)

// ---------------------------------------------------------------------------
// K1: encoder + decoder LSTM. One block per batch. 1024 threads:
// thread (i = tid>>3, q = tid&7) owns ALL 4 gate rows for h-index i over
// k-slice [16q, 16q+16) -> 64 weight floats in VGPRs, and reads only 64B of
// h per step (total 64KB/CU-step vs R2's 256KB -- the measured LDS-return
// bottleneck). h stored skewed (16-float blocks padded to 20 dwords) so the
// 8 q-groups hit disjoint banks. Partials reduced across q with shfl_xor;
// lane q==0 applies activations and updates (c,h). 1 barrier/step,
// double-buffered h.
// ---------------------------------------------------------------------------
__global__ __launch_bounds__(1024, 4) void lstm_kernel(
    const float* __restrict__ x,
    const float* __restrict__ eWih, const float* __restrict__ eWhh, const float* __restrict__ eb,
    const float* __restrict__ dWih, const float* __restrict__ dWhh, const float* __restrict__ db,
    float* __restrict__ encH, float* __restrict__ decH)
{
  const int b   = blockIdx.x;
  const int tid = threadIdx.x;
  const int q   = tid & 7;    // k-slice index
  const int i   = tid >> 3;   // h index 0..127

  __shared__ __align__(16) float xs[TT * FIN];   // 6 KB
  __shared__ __align__(16) float hbuf[2][160];   // skewed h, double-buffered

  if (tid < (TT * FIN / 4))
    ((float4*)xs)[tid] = ((const float4*)(x + (size_t)b * TT * FIN))[tid];
  if (tid < 320) ((float*)hbuf)[tid] = 0.0f;
  float c = 0.0f;  // live in q==0 lanes

  const int xo   = (q < 4) ? 3 * q : 0;   // in-bounds x offset
  const float xz = (q < 4) ? 1.0f : 0.0f;

  int ts = 0;
  #pragma unroll 1
  for (int phase = 0; phase < 2; ++phase) {
    const float* Wih  = phase ? dWih : eWih;
    const float* Whh  = phase ? dWhh : eWhh;
    const float* bias = phase ? db : eb;
    float* Hout       = phase ? decH : encH;

    // recurrent weights: 4 gates x 16 k (k = 16q + 4j + comp)
    float4 wg[4][4];
    #pragma unroll
    for (int g = 0; g < 4; ++g)
      #pragma unroll
      for (int j = 0; j < 4; ++j)
        wg[g][j] = *(const float4*)(Whh + ((g * HH + i) * HH) + 16 * q + 4 * j);

    // input weights: 3 columns (xo..xo+2) of each gate row; zero for q>=4
    float wx[4][3];
    #pragma unroll
    for (int g = 0; g < 4; ++g)
      #pragma unroll
      for (int j = 0; j < 3; ++j)
        wx[g][j] = Wih[(g * HH + i) * FIN + xo + j] * xz;

    const float bi = bias[i], bf = bias[HH + i], bg = bias[2 * HH + i], bo = bias[3 * HH + i];

    #pragma unroll 1
    for (int t = 0; t < TT; ++t, ++ts) {
      __syncthreads();  // h(t) ready in hbuf[ts&1]
      const float* hb = hbuf[ts & 1] + q * 20;
      float4 h0 = *(const float4*)(hb + 0);
      float4 h1 = *(const float4*)(hb + 4);
      float4 h2 = *(const float4*)(hb + 8);
      float4 h3 = *(const float4*)(hb + 12);

      // x contribution (q<4 lanes carry it; others have zero weights)
      const float* xt = xs + t * FIN + xo;
      float x0 = xt[0], x1 = xt[1], x2 = xt[2];
      float ai = wx[0][0] * x0 + wx[0][1] * x1 + wx[0][2] * x2;
      float af = wx[1][0] * x0 + wx[1][1] * x1 + wx[1][2] * x2;
      float ag = wx[2][0] * x0 + wx[2][1] * x1 + wx[2][2] * x2;
      float ao = wx[3][0] * x0 + wx[3][1] * x1 + wx[3][2] * x2;

      ACC4(h0, wg[0][0], ai); ACC4(h0, wg[1][0], af); ACC4(h0, wg[2][0], ag); ACC4(h0, wg[3][0], ao);
      ACC4(h1, wg[0][1], ai); ACC4(h1, wg[1][1], af); ACC4(h1, wg[2][1], ag); ACC4(h1, wg[3][1], ao);
      ACC4(h2, wg[0][2], ai); ACC4(h2, wg[1][2], af); ACC4(h2, wg[2][2], ag); ACC4(h2, wg[3][2], ao);
      ACC4(h3, wg[0][3], ai); ACC4(h3, wg[1][3], af); ACC4(h3, wg[2][3], ag); ACC4(h3, wg[3][3], ao);

      // reduce partials across the 8 q-lanes (lane bits 0-2)
      #pragma unroll
      for (int m = 1; m <= 4; m <<= 1) {
        ai += __shfl_xor(ai, m, 64);
        af += __shfl_xor(af, m, 64);
        ag += __shfl_xor(ag, m, 64);
        ao += __shfl_xor(ao, m, 64);
      }

      if (q == 0) {
        float zi = sigm_f(ai + bi);
        float zf = sigm_f(af + bf);
        float zg = tanh_f(ag + bg);
        float zo = sigm_f(ao + bo);
        c = fmaf(zf, c, zi * zg);
        float hn = zo * tanh_f(c);
        hbuf[(ts + 1) & 1][(i >> 4) * 20 + (i & 15)] = hn;
        Hout[((size_t)b * TT + t) * HH + i] = hn;
      }
    }
  }
}

// ---------------------------------------------------------------------------
// K2: A[b,s,h] = decH[b,s,:]·W1[h,:] + attn_b[h]   (m==0)
//     P[b,t,h] = encH[b,t,:]·W2[h,:]               (m==1)
// grid 1024 = (8 row-tiles x 64 b x 2 m), 256 threads, k-halved LDS W^T.
// ---------------------------------------------------------------------------
__global__ __launch_bounds__(256, 2) void proj_kernel(
    const float* __restrict__ encH, const float* __restrict__ decH,
    const float* __restrict__ attnW, const float* __restrict__ attnb,
    float* __restrict__ Abuf, float* __restrict__ Pbuf)
{
  const int m  = blockIdx.x & 1;
  const int b  = (blockIdx.x >> 1) & 63;
  const int r0 = (blockIdx.x >> 7) * 16;
  const int tid = threadIdx.x;

  __shared__ __align__(16) float WT[64 * 128];  // 32 KB: W^T for a k-half
  __shared__ __align__(16) float Xt[16 * 128];  // 8 KB

  const float* X = (m ? encH : decH) + ((size_t)b * TT + r0) * HH;
  const float* W = attnW + (m ? HH : 0);

  ((float4*)Xt)[tid]       = ((const float4*)X)[tid];
  ((float4*)Xt)[256 + tid] = ((const float4*)X)[256 + tid];

  const int hq = tid & 31, rr = tid >> 5;
  const int h0 = 4 * hq;

  float4 acc0, acc1;
  if (m == 0) { acc0 = *(const float4*)(attnb + h0); acc1 = acc0; }
  else        { acc0 = make_float4(0.f, 0.f, 0.f, 0.f); acc1 = acc0; }

  for (int kb = 0; kb < 2; ++kb) {
    __syncthreads();  // protect WT overwrite
    {
      int h = tid >> 1, koff = (tid & 1) * 32;
      #pragma unroll
      for (int j = 0; j < 8; ++j) {
        float4 v = *(const float4*)(W + h * 256 + kb * 64 + koff + 4 * j);
        int kp = koff + 4 * j;
        WT[(kp + 0) * 128 + h] = v.x;
        WT[(kp + 1) * 128 + h] = v.y;
        WT[(kp + 2) * 128 + h] = v.z;
        WT[(kp + 3) * 128 + h] = v.w;
      }
    }
    __syncthreads();
    const float* xr0 = Xt + (2 * rr) * 128 + kb * 64;
    const float* xr1 = xr0 + 128;
    #pragma unroll
    for (int k4 = 0; k4 < 64; k4 += 4) {
      float4 xa = *(const float4*)(xr0 + k4);
      float4 xb = *(const float4*)(xr1 + k4);
      float4 w0 = *(const float4*)&WT[(k4 + 0) * 128 + h0];
      float4 w1 = *(const float4*)&WT[(k4 + 1) * 128 + h0];
      float4 w2 = *(const float4*)&WT[(k4 + 2) * 128 + h0];
      float4 w3 = *(const float4*)&WT[(k4 + 3) * 128 + h0];
      FMA4S(acc0, xa.x, w0); FMA4S(acc0, xa.y, w1);
      FMA4S(acc0, xa.z, w2); FMA4S(acc0, xa.w, w3);
      FMA4S(acc1, xb.x, w0); FMA4S(acc1, xb.y, w1);
      FMA4S(acc1, xb.z, w2); FMA4S(acc1, xb.w, w3);
    }
  }
  float* O = (m ? Pbuf : Abuf) + ((size_t)b * TT + r0) * HH;
  *(float4*)(O + (2 * rr) * 128 + h0)     = acc0;
  *(float4*)(O + (2 * rr + 1) * 128 + h0) = acc1;
}

// ---------------------------------------------------------------------------
// K3: attention + output. Block = (b, 16 decoder steps). 512 threads.
// t halved so LDS stays < 64 KB; P transposed into LDS with XOR-quad swizzle.
// ---------------------------------------------------------------------------
__global__ __launch_bounds__(512, 2) void attn_kernel(
    const float* __restrict__ encH, const float* __restrict__ decH,
    const float* __restrict__ Abuf, const float* __restrict__ Pbuf,
    const float* __restrict__ vw, const float* __restrict__ outW,
    const float* __restrict__ outb, float* __restrict__ out)
{
  const int b  = blockIdx.x >> 3;
  const int s0 = (blockIdx.x & 7) * 16;
  const int tid = threadIdx.x;

  __shared__ __align__(16) float buf[64 * 128];    // 32 KB: P^T-half (swizzled), later encH-half
  __shared__ __align__(16) float a_lds[16 * 128];  // 8 KB: A tile, later ctx
  __shared__ __align__(16) float sc[16 * 128];     // 8 KB: scores -> weights
  __shared__ __align__(16) float dh[16 * 128];     // 8 KB: decH tile
  __shared__ __align__(16) float vl[HH];

  ((float4*)a_lds)[tid] = ((const float4*)(Abuf + ((size_t)b * TT + s0) * HH))[tid];
  ((float4*)dh)[tid]    = ((const float4*)(decH + ((size_t)b * TT + s0) * HH))[tid];
  if (tid < 32) ((float4*)vl)[tid] = ((const float4*)vw)[tid];

  const int u  = tid & 31;
  const int sl = tid >> 5;   // 0..15 decoder-step within tile
  const int uq = u & 15;     // t-quad within half
  const int uh = u >> 4;     // 0/1 h-half

  // ---- energies/scores ----
  for (int half = 0; half < 2; ++half) {
    const int tbase = half * 64;
    __syncthreads();  // prev buf use done (also covers initial staging)
    #pragma unroll
    for (int i = 0; i < 4; ++i) {
      int flat = i * 2048 + tid * 4;
      int tp = flat >> 7;        // 0..63
      int h0 = flat & 127;
      float4 v = *(const float4*)(Pbuf + ((size_t)b * TT + tbase + tp) * HH + h0);
      int tq = tp >> 2, tr = tp & 3;
      buf[(h0 + 0) * 64 + 4 * ((tq ^ ((h0 + 0) >> 2)) & 15) + tr] = v.x;
      buf[(h0 + 1) * 64 + 4 * ((tq ^ ((h0 + 1) >> 2)) & 15) + tr] = v.y;
      buf[(h0 + 2) * 64 + 4 * ((tq ^ ((h0 + 2) >> 2)) & 15) + tr] = v.z;
      buf[(h0 + 3) * 64 + 4 * ((tq ^ ((h0 + 3) >> 2)) & 15) + tr] = v.w;
    }
    __syncthreads();
    float4 acc = make_float4(0.f, 0.f, 0.f, 0.f);
    const float* arow = a_lds + sl * 128;
    #pragma unroll 8
    for (int hh = 0; hh < 64; ++hh) {
      int h = uh * 64 + hh;
      float ah = arow[h];
      float vh = vl[h];
      float4 p4 = *(const float4*)&buf[h * 64 + 4 * ((uq ^ ((h >> 2) & 15)) & 15)];
      acc.x = fmaf(vh, tanh_f(ah + p4.x), acc.x);
      acc.y = fmaf(vh, tanh_f(ah + p4.y), acc.y);
      acc.z = fmaf(vh, tanh_f(ah + p4.z), acc.z);
      acc.w = fmaf(vh, tanh_f(ah + p4.w), acc.w);
    }
    acc.x += __shfl_xor(acc.x, 16, 64);
    acc.y += __shfl_xor(acc.y, 16, 64);
    acc.z += __shfl_xor(acc.z, 16, 64);
    acc.w += __shfl_xor(acc.w, 16, 64);
    if (uh == 0) *(float4*)&sc[sl * 128 + tbase + 4 * uq] = acc;
  }
  __syncthreads();

  // ---- softmax over t (per s row; 32 lanes x f4 = 128) ----
  {
    float4 sv = *(const float4*)&sc[sl * 128 + 4 * u];
    float mx = fmaxf(fmaxf(sv.x, sv.y), fmaxf(sv.z, sv.w));
    #pragma unroll
    for (int msk = 1; msk <= 16; msk <<= 1) mx = fmaxf(mx, __shfl_xor(mx, msk, 64));
    float4 e;
    e.x = fexp2(LOG2E * (sv.x - mx));
    e.y = fexp2(LOG2E * (sv.y - mx));
    e.z = fexp2(LOG2E * (sv.z - mx));
    e.w = fexp2(LOG2E * (sv.w - mx));
    float sm = (e.x + e.y) + (e.z + e.w);
    #pragma unroll
    for (int msk = 1; msk <= 16; msk <<= 1) sm += __shfl_xor(sm, msk, 64);
    float r = frcp(sm);
    e.x *= r; e.y *= r; e.z *= r; e.w *= r;
    *(float4*)&sc[sl * 128 + 4 * u] = e;
  }

  // ---- ctx = w @ encH ----
  float4 ctx = make_float4(0.f, 0.f, 0.f, 0.f);
  const int h0c = 4 * u;
  for (int half = 0; half < 2; ++half) {
    const int tbase = half * 64;
    __syncthreads();  // buf reuse; also orders softmax writes before reads
    #pragma unroll
    for (int i = 0; i < 4; ++i) {
      int flat = i * 2048 + tid * 4;
      int tp = flat >> 7;
      int hh0 = flat & 127;
      *(float4*)&buf[tp * 128 + hh0] =
          *(const float4*)(encH + ((size_t)b * TT + tbase + tp) * HH + hh0);
    }
    __syncthreads();
    const float* wrow = sc + sl * 128 + tbase;
    #pragma unroll 8
    for (int tp = 0; tp < 64; ++tp) {
      float wt = wrow[tp];
      float4 e4 = *(const float4*)&buf[tp * 128 + h0c];
      FMA4S(ctx, wt, e4);
    }
  }
  __syncthreads();
  *(float4*)&a_lds[sl * 128 + h0c] = ctx;  // overlay A tile with ctx
  __syncthreads();

  // ---- out = [decH, ctx] @ outW^T + outb ----
  if (tid < 192) {
    int s = tid / 12, f = tid % 12;
    float acc = outb[f];
    const float4* w4 = (const float4*)(outW + f * 256);
    const float4* d4 = (const float4*)(dh + s * 128);
    const float4* c4 = (const float4*)(a_lds + s * 128);
    #pragma unroll
    for (int k = 0; k < 32; ++k) {
      float4 wv = w4[k], dv = d4[k];
      acc = fmaf(wv.x, dv.x, acc); acc = fmaf(wv.y, dv.y, acc);
      acc = fmaf(wv.z, dv.z, acc); acc = fmaf(wv.w, dv.w, acc);
    }
    #pragma unroll
    for (int k = 0; k < 32; ++k) {
      float4 wv = w4[32 + k], cv = c4[k];
      acc = fmaf(wv.x, cv.x, acc); acc = fmaf(wv.y, cv.y, acc);
      acc = fmaf(wv.z, cv.z, acc); acc = fmaf(wv.w, cv.w, acc);
    }
    out[((size_t)b * TT + s0 + s) * FIN + f] = acc;
  }
}

// ---------------------------------------------------------------------------
extern "C" void kernel_launch(void* const* d_in, const int* in_sizes, int n_in,
                              void* d_out, int out_size, void* d_ws, size_t ws_size,
                              hipStream_t stream)
{
  const float* x     = (const float*)d_in[0];
  const float* eWih  = (const float*)d_in[1];
  const float* eWhh  = (const float*)d_in[2];
  const float* eb    = (const float*)d_in[3];
  const float* dWih  = (const float*)d_in[4];
  const float* dWhh  = (const float*)d_in[5];
  const float* db    = (const float*)d_in[6];
  const float* attnW = (const float*)d_in[7];
  const float* attnb = (const float*)d_in[8];
  const float* vw    = (const float*)d_in[9];
  const float* outW  = (const float*)d_in[10];
  const float* outb  = (const float*)d_in[11];
  float* out = (float*)d_out;

  float* ws   = (float*)d_ws;
  const size_t SEG = (size_t)BB * TT * HH;  // 1,048,576 floats = 4 MB
  float* encH = ws;
  float* decH = ws + SEG;
  float* Abuf = ws + 2 * SEG;
  float* Pbuf = ws + 3 * SEG;

  lstm_kernel<<<64, 1024, 0, stream>>>(x, eWih, eWhh, eb, dWih, dWhh, db, encH, decH);
  proj_kernel<<<1024, 256, 0, stream>>>(encH, decH, attnW, attnb, Abuf, Pbuf);
  attn_kernel<<<512, 512, 0, stream>>>(encH, decH, Abuf, Pbuf, vw, outW, outb, out);
}